// Round 12
// baseline (350.961 us; speedup 1.0000x reference)
//
#include <hip/hip_runtime.h>
#include <hip/hip_fp16.h>
#include <math.h>

#define DEV static __device__ __forceinline__

typedef _Float16 f16;
typedef __attribute__((ext_vector_type(4))) _Float16 f16x4;
typedef __attribute__((ext_vector_type(8))) _Float16 f16x8;
typedef __attribute__((ext_vector_type(4))) float f32x4;

DEV f16x8 ld8(const f16* p) { return *(const f16x8*)p; }
DEV f32x4 mfma32(f16x8 a, f16x8 b, f32x4 c) {
  return __builtin_amdgcn_mfma_f32_16x16x32_f16(a, b, c, 0, 0, 0);
}
DEV float ftanh(float x) {
  float e = __expf(2.f * x);
  return 1.f - 2.f / (e + 1.f);
}

// ---------------- prep: pack ODE+FC weights f16 row-major [out][in] ----------------
__global__ __launch_bounds__(64) void prep_kernel(
    const float* __restrict__ Bm,
    const float* __restrict__ dr1_w, const float* __restrict__ dr1_b,
    const float* __restrict__ dr2_w, const float* __restrict__ dr2_b,
    const float* __restrict__ tau1_w, const float* __restrict__ tau1_b,
    const float* __restrict__ tau2_w, const float* __restrict__ tau2_b,
    const float* __restrict__ fc_w, const float* __restrict__ fc_b,
    char* __restrict__ wsb) {
  f16* dr1h = (f16*)(wsb);
  f16* tau1h = (f16*)(wsb + 16384);
  f16* dr2h = (f16*)(wsb + 32768);
  f16* tau2h = (f16*)(wsb + 49152);
  f16* Ah = (f16*)(wsb + 65536);
  f16* fch = (f16*)(wsb + 73728);
  float* fb = (float*)(wsb + 98304);

  const int t = threadIdx.x, blk = blockIdx.x;
  if (blk < 16) {
    int row = blk * 4 + (t >> 4), c0 = 4 * (t & 15);
    float a0 = 0.f, a1 = 0.f, a2 = 0.f, a3 = 0.f;
    for (int m = 0; m < 64; ++m) {
      float br = Bm[m * 64 + row];
      a0 = fmaf(br, Bm[m * 64 + c0 + 0], a0);
      a1 = fmaf(br, Bm[m * 64 + c0 + 1], a1);
      a2 = fmaf(br, Bm[m * 64 + c0 + 2], a2);
      a3 = fmaf(br, Bm[m * 64 + c0 + 3], a3);
    }
    Ah[row * 64 + c0 + 0] = (f16)(-a0);
    Ah[row * 64 + c0 + 1] = (f16)(-a1);
    Ah[row * 64 + c0 + 2] = (f16)(-a2);
    Ah[row * 64 + c0 + 3] = (f16)(-a3);
  } else if (blk < 48) {
    int idx = (blk - 16) * 64 + t;
    int row = idx >> 4, c0 = 4 * (idx & 15);
#pragma unroll
    for (int j = 0; j < 4; ++j) {
      dr1h[row * 64 + c0 + j] = (f16)dr1_w[row * 64 + c0 + j];
      tau1h[row * 64 + c0 + j] = (f16)tau1_w[row * 65 + c0 + j];
    }
  } else if (blk < 80) {
    int idx = (blk - 48) * 64 + t;
    int row = idx >> 5, c0 = 4 * (idx & 31);
#pragma unroll
    for (int j = 0; j < 4; ++j) {
      dr2h[row * 128 + c0 + j] = (f16)dr2_w[row * 128 + c0 + j];
      tau2h[row * 128 + c0 + j] = (f16)tau2_w[row * 128 + c0 + j];
    }
  } else if (blk < 128) {
    int idx = (blk - 80) * 64 + t;
    int row = idx >> 4, c0 = 4 * (idx & 15);
#pragma unroll
    for (int j = 0; j < 4; ++j)
      fch[row * 64 + c0 + j] = (f16)fc_w[row * 64 + c0 + j];
  } else {
    for (int i = (blk - 128) * 64 + t; i < 704; i += 128) {
      float v;
      if (i < 128) v = dr1_b[i];
      else if (i < 256) v = tau1_b[i - 128];
      else if (i < 320) v = dr2_b[i - 256];
      else if (i < 384) v = tau2_b[i - 320];
      else if (i < 512) v = tau1_w[(i - 384) * 65 + 64];
      else v = fc_b[i - 512];
      fb[i] = v;
    }
  }
}

// ---------------- prep_tf: tf weights -> f16 (unpadded row-major) + PE table -------
__global__ __launch_bounds__(256) void prep_tf(
    const float* __restrict__ conv_w, const float* __restrict__ attn_w,
    const float* __restrict__ out_w, const float* __restrict__ ff1_w,
    const float* __restrict__ ff2_w, const float* __restrict__ conv_b,
    f16* __restrict__ tfw, float* __restrict__ pecb) {
  int idx = blockIdx.x * 256 + threadIdx.x;
  if (idx >= 96256) return;
  if (idx >= 94208) {
    int e = idx - 94208;  // 0..2047
    int i = 1 + (e >> 6), dd = e & 63;
    float freq = __expf(-0.14391157f * (float)(dd & ~1));
    float ang = (float)i * freq;
    pecb[e] = ((dd & 1) ? cosf(ang) : sinf(ang)) + conv_b[dd];
    return;
  }
  float v;
  if (idx < 8192) {
    int dd = idx >> 7, k = idx & 127;
    v = conv_w[dd * 128 + (k & 7) * 16 + (k >> 3)];
  } else {
    int r = idx - 8192;
    int l = r / 28672, q = r - l * 28672;
    if (q < 12288) v = attn_w[l * 12288 + q];
    else if (q < 16384) v = out_w[l * 4096 + (q - 12288)];
    else if (q < 22528) v = ff1_w[l * 6144 + (q - 16384)];
    else v = ff2_w[l * 6144 + (q - 22528)];
  }
  tfw[idx] = (f16)v;
}

// ---------------- transformer v6: f16 master, 38.8 KB LDS, 4 blocks/CU -------------
// LDS: Zh f16[48][72] @0 (master) | Qh/oh @6912 | Kh @13824 | VT f16[64][40] @20736
//  | P f16[4][33][40] @25856 + guard -> 38800 total
//  aliases: Sx f16[32][136] @6912 (prologue) ; f1h f16[48][104] @13824 (ff phase)
__global__ __launch_bounds__(256, 4) void tf_kernel(
    const float* __restrict__ x, const f16* __restrict__ tfw,
    const float* __restrict__ pecb, const float* __restrict__ cls,
    const float* __restrict__ attn_b, const float* __restrict__ out_b,
    const float* __restrict__ ln1_g, const float* __restrict__ ln1_b,
    const float* __restrict__ ln2_g, const float* __restrict__ ln2_b,
    const float* __restrict__ ff1_b, const float* __restrict__ ff2_b,
    float* __restrict__ zc) {
  __shared__ __align__(16) unsigned char SH[38800];
  f16* Zh = (f16*)SH;
  f16* Qh = (f16*)(SH + 6912);
  f16* Kh = (f16*)(SH + 13824);
  f16* VT = (f16*)(SH + 20736);
  f16* P = (f16*)(SH + 25856);
  f16* Sx = (f16*)(SH + 6912);
  f16* f1h = (f16*)(SH + 13824);
  f16* oh = Qh;

  const int t = threadIdx.x;
  const int b = blockIdx.x;
  const int w = t >> 6, lane = t & 63;
  const int c16 = lane & 15, q4 = lane >> 4;
  const int dcol = w * 16 + c16;
  const int d4 = w * 16 + q4 * 4;
  const int nrow = t >> 2, nl4 = t & 3;

  // ---- prologue: x->Sx(f16), zero Zh pad rows + P(+guard), cls row ----
  {
    const float4* xg = (const float4*)(x + (size_t)b * 4096);
    for (int i = t; i < 1024; i += 256) {
      int n = i >> 5, jj = i & 31;
      float4 v = xg[i];
      *(f16x4*)(Sx + n * 136 + jj * 4) = f16x4{(f16)v.x, (f16)v.y, (f16)v.z, (f16)v.w};
    }
    unsigned* zp = (unsigned*)(Zh + 33 * 72);
    for (int i = t; i < 540; i += 256) zp[i] = 0u;
    uint4 z4{0, 0, 0, 0};
    uint4* pp = (uint4*)P;
    for (int i = t; i < 809; i += 256) pp[i] = z4;  // P + guard (12944 B)
    if (t < 64) Zh[t] = (f16)(cls[t] + ((t & 1) ? 1.0f : 0.0f));
  }
  __syncthreads();

  // ---- patch embed (swapped) + PE table ----
  {
    f16x8 cw[4];
#pragma unroll
    for (int kb = 0; kb < 4; ++kb)
      cw[kb] = ld8(tfw + dcol * 128 + kb * 32 + q4 * 8);
#pragma unroll
    for (int it = 0; it < 2; ++it) {
      f32x4 acc = {};
#pragma unroll
      for (int kb = 0; kb < 4; ++kb)
        acc = mfma32(cw[kb], ld8(Sx + (it * 16 + c16) * 136 + kb * 32 + q4 * 8), acc);
      int n = it * 16 + c16;
      float4 pe = *(const float4*)(pecb + n * 64 + d4);
      *(f16x4*)(Zh + (n + 1) * 72 + d4) =
          f16x4{(f16)(acc[0] + pe.x), (f16)(acc[1] + pe.y),
                (f16)(acc[2] + pe.z), (f16)(acc[3] + pe.w)};
    }
  }
  __syncthreads();

  for (int l = 0; l < 3; ++l) {
    const f16* lw = tfw + 8192 + l * 28672;
    const int ntile = (l == 2) ? 1 : 3;
    const bool has2 = (w < 2);
    const int j1f = has2 ? (w + 4) * 16 + c16 : dcol;
    const int j1b = has2 ? (w + 4) * 16 + q4 * 4 : d4;

    // ---- layer-resident weight A-fragments ----
    f16x8 wq0 = ld8(lw + dcol * 64 + q4 * 8);
    f16x8 wq1 = ld8(lw + dcol * 64 + 32 + q4 * 8);
    f16x8 wk0 = ld8(lw + (64 + dcol) * 64 + q4 * 8);
    f16x8 wk1 = ld8(lw + (64 + dcol) * 64 + 32 + q4 * 8);
    f16x8 wv0 = ld8(lw + (128 + dcol) * 64 + q4 * 8);
    f16x8 wv1 = ld8(lw + (128 + dcol) * 64 + 32 + q4 * 8);
    f16x8 ow0 = ld8(lw + 12288 + dcol * 64 + q4 * 8);
    f16x8 ow1 = ld8(lw + 12288 + dcol * 64 + 32 + q4 * 8);
    f16x8 f1w00 = ld8(lw + 16384 + dcol * 64 + q4 * 8);
    f16x8 f1w01 = ld8(lw + 16384 + dcol * 64 + 32 + q4 * 8);
    f16x8 f1w10 = ld8(lw + 16384 + j1f * 64 + q4 * 8);
    f16x8 f1w11 = ld8(lw + 16384 + j1f * 64 + 32 + q4 * 8);
    f16x8 fw20 = ld8(lw + 22528 + dcol * 96 + q4 * 8);
    f16x8 fw21 = ld8(lw + 22528 + dcol * 96 + 32 + q4 * 8);
    f16x8 fw22 = ld8(lw + 22528 + dcol * 96 + 64 + q4 * 8);
    float4 bq4 = *(const float4*)(attn_b + l * 192 + d4);
    float4 bk4 = *(const float4*)(attn_b + l * 192 + 64 + d4);
    float bv = attn_b[l * 192 + 128 + dcol];
    float4 ob4 = *(const float4*)(out_b + l * 64 + d4);
    float4 f1b0 = *(const float4*)(ff1_b + l * 96 + d4);
    float4 f1b1 = *(const float4*)(ff1_b + l * 96 + j1b);
    float4 f2b4 = *(const float4*)(ff2_b + l * 64 + d4);

    // ---- P1: qkv ----
    {
      f16x8 zr0[3], zr1[3];
#pragma unroll
      for (int it = 0; it < 3; ++it) {
        zr0[it] = ld8(Zh + (it * 16 + c16) * 72 + q4 * 8);
        zr1[it] = ld8(Zh + (it * 16 + c16) * 72 + 32 + q4 * 8);
      }
#pragma unroll
      for (int it = 0; it < 3; ++it) {
        f32x4 aq = {}, ak = {}, av = {};
        aq = mfma32(wq0, zr0[it], aq); aq = mfma32(wq1, zr1[it], aq);
        ak = mfma32(wk0, zr0[it], ak); ak = mfma32(wk1, zr1[it], ak);
        av = mfma32(zr0[it], wv0, av); av = mfma32(zr1[it], wv1, av);
        int i = it * 16 + c16;
        *(f16x4*)(Qh + i * 72 + d4) =
            f16x4{(f16)((aq[0] + bq4.x) * 0.25f), (f16)((aq[1] + bq4.y) * 0.25f),
                  (f16)((aq[2] + bq4.z) * 0.25f), (f16)((aq[3] + bq4.w) * 0.25f)};
        *(f16x4*)(Kh + i * 72 + d4) =
            f16x4{(f16)(ak[0] + bk4.x), (f16)(ak[1] + bk4.y),
                  (f16)(ak[2] + bk4.z), (f16)(ak[3] + bk4.w)};
        if (it < 2) {
          *(f16x4*)(VT + dcol * 40 + it * 16 + q4 * 4) =
              f16x4{(f16)(av[0] + bv), (f16)(av[1] + bv),
                    (f16)(av[2] + bv), (f16)(av[3] + bv)};
        } else if (q4 == 0) {
          VT[dcol * 40 + 32] = (f16)(av[0] + bv);
        }
      }
    }

    // ---- P2: S^T = K.Q^T -> masked softmax -> O^T = V^T.P^T ----
    {
      f16x8 zf = {};
      f16x8 kf0 = (q4 < 2) ? ld8(Kh + (c16) * 72 + w * 16 + q4 * 8) : zf;
      f16x8 kf1 = (q4 < 2) ? ld8(Kh + (16 + c16) * 72 + w * 16 + q4 * 8) : zf;
      f16x8 kf2 = (q4 < 2) ? ld8(Kh + (32 + c16) * 72 + w * 16 + q4 * 8) : zf;
      f16x8 vf = ld8(VT + dcol * 40 + q4 * 8);
      float vt32[4];
#pragma unroll
      for (int r = 0; r < 4; ++r) vt32[r] = (float)VT[(d4 + r) * 40 + 32];
      f16* Ph = P + w * 1320;
#pragma unroll
      for (int it = 0; it < 3; ++it) {
        if (it >= ntile) break;
        f16x8 qf = (q4 < 2) ? ld8(Qh + (it * 16 + c16) * 72 + w * 16 + q4 * 8) : zf;
        f32x4 zz = {};
        f32x4 s0 = mfma32(kf0, qf, zz);
        f32x4 s1 = mfma32(kf1, qf, zz);
        f32x4 s2 = mfma32(kf2, qf, zz);
        float m = -1e30f;
#pragma unroll
        for (int r = 0; r < 4; ++r) m = fmaxf(m, fmaxf(s0[r], s1[r]));
        if (q4 == 0) m = fmaxf(m, s2[0]);
        m = fmaxf(m, __shfl_xor(m, 16));
        m = fmaxf(m, __shfl_xor(m, 32));
        float e0[4], e1[4], su = 0.f;
#pragma unroll
        for (int r = 0; r < 4; ++r) {
          e0[r] = __expf(s0[r] - m); e1[r] = __expf(s1[r] - m);
          su += e0[r] + e1[r];
        }
        float e2 = (q4 == 0) ? __expf(s2[0] - m) : 0.f;
        su += e2;
        su += __shfl_xor(su, 16);
        su += __shfl_xor(su, 32);
        float inv = 1.f / su;
        int i = it * 16 + c16;
        if (i < 33) {
          *(f16x4*)(Ph + i * 40 + q4 * 4) =
              f16x4{(f16)(e0[0] * inv), (f16)(e0[1] * inv),
                    (f16)(e0[2] * inv), (f16)(e0[3] * inv)};
          *(f16x4*)(Ph + i * 40 + 16 + q4 * 4) =
              f16x4{(f16)(e1[0] * inv), (f16)(e1[1] * inv),
                    (f16)(e1[2] * inv), (f16)(e1[3] * inv)};
          if (q4 == 0) Ph[i * 40 + 32] = (f16)(e2 * inv);
        }
      }
#pragma unroll
      for (int it = 0; it < 3; ++it) {
        if (it >= ntile) break;
        int i = it * 16 + c16;
        f16x8 pf = ld8(Ph + i * 40 + q4 * 8);   // i>=33 reads next region/guard: finite, discarded
        f32x4 zz = {};
        f32x4 acc = mfma32(vf, pf, zz);
        float p32 = (float)Ph[i * 40 + 32];
        *(f16x4*)(oh + i * 72 + d4) =
            f16x4{(f16)(acc[0] + vt32[0] * p32), (f16)(acc[1] + vt32[1] * p32),
                  (f16)(acc[2] + vt32[2] * p32), (f16)(acc[3] + vt32[3] * p32)};
      }
    }
    __syncthreads();

    // ---- P3: out-proj + residual RMW on f16 master ----
#pragma unroll
    for (int it = 0; it < 3; ++it) {
      if (it >= ntile) break;
      int i = it * 16 + c16;
      f32x4 acc = {};
      acc = mfma32(ow0, ld8(oh + i * 72 + q4 * 8), acc);
      acc = mfma32(ow1, ld8(oh + i * 72 + 32 + q4 * 8), acc);
      if (it < 2 || c16 == 0) {
        f16x4 zr = *(f16x4*)(Zh + i * 72 + d4);
        *(f16x4*)(Zh + i * 72 + d4) =
            f16x4{(f16)((float)zr[0] + acc[0] + ob4.x),
                  (f16)((float)zr[1] + acc[1] + ob4.y),
                  (f16)((float)zr[2] + acc[2] + ob4.z),
                  (f16)((float)zr[3] + acc[3] + ob4.w)};
      }
    }
    __syncthreads();

    // ---- P4: fused LN1 on f16 master ----
    {
      int rows = (l == 2) ? 16 : 33;
      if (nrow < rows) {
        f16* zr = Zh + nrow * 72 + nl4 * 16;
        f16x8 h0 = ld8(zr), h1 = ld8(zr + 8);
        float v[16];
#pragma unroll
        for (int j = 0; j < 8; ++j) { v[j] = (float)h0[j]; v[8 + j] = (float)h1[j]; }
        float su = 0.f, ss = 0.f;
#pragma unroll
        for (int j = 0; j < 16; ++j) { su += v[j]; ss = fmaf(v[j], v[j], ss); }
        su += __shfl_xor(su, 1); ss += __shfl_xor(ss, 1);
        su += __shfl_xor(su, 2); ss += __shfl_xor(ss, 2);
        float m = su * 0.015625f;
        float rr = rsqrtf(ss * 0.015625f - m * m + 1e-5f);
        const float4* gg = (const float4*)(ln1_g + l * 64 + nl4 * 16);
        const float4* bb = (const float4*)(ln1_b + l * 64 + nl4 * 16);
#pragma unroll
        for (int g4 = 0; g4 < 4; ++g4) {
          float4 G = gg[g4], B = bb[g4];
          *(f16x4*)(zr + g4 * 4) =
              f16x4{(f16)((v[g4 * 4 + 0] - m) * rr * G.x + B.x),
                    (f16)((v[g4 * 4 + 1] - m) * rr * G.y + B.y),
                    (f16)((v[g4 * 4 + 2] - m) * rr * G.z + B.z),
                    (f16)((v[g4 * 4 + 3] - m) * rr * G.w + B.w)};
        }
      }
    }
    __syncthreads();

    // ---- P5: ff1 ----
    {
      f16x8 zr0[3], zr1[3];
#pragma unroll
      for (int it = 0; it < 3; ++it) {
        zr0[it] = ld8(Zh + (it * 16 + c16) * 72 + q4 * 8);
        zr1[it] = ld8(Zh + (it * 16 + c16) * 72 + 32 + q4 * 8);
      }
#pragma unroll
      for (int it = 0; it < 3; ++it) {
        if (it >= ntile) break;
        int i = it * 16 + c16;
        f32x4 acc = {};
        acc = mfma32(f1w00, zr0[it], acc);
        acc = mfma32(f1w01, zr1[it], acc);
        *(f16x4*)(f1h + i * 104 + d4) =
            f16x4{(f16)fmaxf(acc[0] + f1b0.x, 0.f), (f16)fmaxf(acc[1] + f1b0.y, 0.f),
                  (f16)fmaxf(acc[2] + f1b0.z, 0.f), (f16)fmaxf(acc[3] + f1b0.w, 0.f)};
        if (has2) {
          f32x4 a2 = {};
          a2 = mfma32(f1w10, zr0[it], a2);
          a2 = mfma32(f1w11, zr1[it], a2);
          *(f16x4*)(f1h + i * 104 + j1b) =
              f16x4{(f16)fmaxf(a2[0] + f1b1.x, 0.f), (f16)fmaxf(a2[1] + f1b1.y, 0.f),
                    (f16)fmaxf(a2[2] + f1b1.z, 0.f), (f16)fmaxf(a2[3] + f1b1.w, 0.f)};
        }
      }
    }
    __syncthreads();

    // ---- P6: ff2 + residual RMW ----
#pragma unroll
    for (int it = 0; it < 3; ++it) {
      if (it >= ntile) break;
      int i = it * 16 + c16;
      f32x4 acc = {};
      acc = mfma32(fw20, ld8(f1h + i * 104 + q4 * 8), acc);
      acc = mfma32(fw21, ld8(f1h + i * 104 + 32 + q4 * 8), acc);
      acc = mfma32(fw22, ld8(f1h + i * 104 + 64 + q4 * 8), acc);
      if (it < 2 || c16 == 0) {
        f16x4 zr = *(f16x4*)(Zh + i * 72 + d4);
        *(f16x4*)(Zh + i * 72 + d4) =
            f16x4{(f16)((float)zr[0] + acc[0] + f2b4.x),
                  (f16)((float)zr[1] + acc[1] + f2b4.y),
                  (f16)((float)zr[2] + acc[2] + f2b4.z),
                  (f16)((float)zr[3] + acc[3] + f2b4.w)};
      }
    }
    __syncthreads();

    // ---- P7: fused LN2 (+ zc on last layer) ----
    {
      int rows = (l == 2) ? 1 : 33;
      if (nrow < rows) {
        f16* zr = Zh + nrow * 72 + nl4 * 16;
        f16x8 h0 = ld8(zr), h1 = ld8(zr + 8);
        float v[16];
#pragma unroll
        for (int j = 0; j < 8; ++j) { v[j] = (float)h0[j]; v[8 + j] = (float)h1[j]; }
        float su = 0.f, ss = 0.f;
#pragma unroll
        for (int j = 0; j < 16; ++j) { su += v[j]; ss = fmaf(v[j], v[j], ss); }
        su += __shfl_xor(su, 1); ss += __shfl_xor(ss, 1);
        su += __shfl_xor(su, 2); ss += __shfl_xor(ss, 2);
        float m = su * 0.015625f;
        float rr = rsqrtf(ss * 0.015625f - m * m + 1e-5f);
        const float4* gg = (const float4*)(ln2_g + l * 64 + nl4 * 16);
        const float4* bb = (const float4*)(ln2_b + l * 64 + nl4 * 16);
        if (l == 2) {
          float4* zo = (float4*)(zc + (size_t)b * 64 + nl4 * 16);
#pragma unroll
          for (int g4 = 0; g4 < 4; ++g4) {
            float4 G = gg[g4], B = bb[g4];
            zo[g4] = make_float4((v[g4 * 4 + 0] - m) * rr * G.x + B.x,
                                 (v[g4 * 4 + 1] - m) * rr * G.y + B.y,
                                 (v[g4 * 4 + 2] - m) * rr * G.z + B.z,
                                 (v[g4 * 4 + 3] - m) * rr * G.w + B.w);
          }
        } else {
#pragma unroll
          for (int g4 = 0; g4 < 4; ++g4) {
            float4 G = gg[g4], B = bb[g4];
            *(f16x4*)(zr + g4 * 4) =
                f16x4{(f16)((v[g4 * 4 + 0] - m) * rr * G.x + B.x),
                      (f16)((v[g4 * 4 + 1] - m) * rr * G.y + B.y),
                      (f16)((v[g4 * 4 + 2] - m) * rr * G.z + B.z),
                      (f16)((v[g4 * 4 + 3] - m) * rr * G.w + B.w)};
          }
        }
      }
    }
    __syncthreads();
  }
}

// ---------------- ODE v4: 8 rows/block, 512 blocks, 2 blocks/CU ----------------
__global__ __launch_bounds__(256, 2) void ode_kernel(
    const char* __restrict__ wsb, const float* __restrict__ zc,
    float* __restrict__ out) {
  const f16* dr1h = (const f16*)(wsb);
  const f16* tau1h = (const f16*)(wsb + 16384);
  const f16* Ah = (const f16*)(wsb + 65536);
  const f16* fch = (const f16*)(wsb + 73728);
  const float* fb = (const float*)(wsb + 98304);

  __shared__ __align__(16) f16 dr2s[64 * 128];
  __shared__ __align__(16) f16 tau2s[64 * 128];
  __shared__ __align__(16) f16 ztL[16 * 64];
  __shared__ __align__(16) f16 hdL[16 * 128];
  __shared__ __align__(16) f16 htL[16 * 128];

  const int t = threadIdx.x;
  const int w = t >> 6;              // 0..3
  const int lane = t & 63;
  const int c16 = lane & 15, q4 = lane >> 4;
  const int b0 = blockIdx.x * 8;     // 8 batch rows per block
  const int swz = (c16 & 7) << 3;

  for (int i = t; i < 2048; i += 256) {
    int m = i >> 10, gi = i & 1023, row = gi >> 4, g = gi & 15;
    uint4 v = ((const uint4*)(wsb + 32768 + m * 16384))[gi];
    ((uint4*)(m ? tau2s : dr2s))[row * 16 + (g ^ (row & 7))] = v;
  }

  f16x8 dr1B[2][2], tau1B[2][2], AB[2];
#pragma unroll
  for (int j = 0; j < 2; ++j) {
    int cth = w * 2 + j;
#pragma unroll
    for (int kb = 0; kb < 2; ++kb) {
      dr1B[j][kb] = ld8(dr1h + (cth * 16 + c16) * 64 + kb * 32 + q4 * 8);
      tau1B[j][kb] = ld8(tau1h + (cth * 16 + c16) * 64 + kb * 32 + q4 * 8);
    }
  }
#pragma unroll
  for (int kb = 0; kb < 2; ++kb)
    AB[kb] = ld8(Ah + (w * 16 + c16) * 64 + kb * 32 + q4 * 8);
  float dr1b[2], tau1b[2], t1t[2];
#pragma unroll
  for (int j = 0; j < 2; ++j) {
    int cc = (w * 2 + j) * 16 + c16;
    dr1b[j] = fb[cc]; tau1b[j] = fb[128 + cc]; t1t[j] = fb[384 + cc];
  }
  float dr2b = fb[256 + w * 16 + c16];
  float tau2b = fb[320 + w * 16 + c16];

  // rows q4*4+r; valid global rows = 0..7 (clamped via &7 for q4>=2 duplicates)
  float zt[4];
#pragma unroll
  for (int r = 0; r < 4; ++r) {
    int gr = (q4 * 4 + r) & 7;
    zt[r] = zc[(size_t)(b0 + gr) * 64 + w * 16 + c16];
  }

  __syncthreads();

  float tm = 0.f;
  for (int s = 0; s < 32; ++s) {
#pragma unroll
    for (int r = 0; r < 4; ++r) {
      int row = q4 * 4 + r;
      ztL[row * 64 + ((w * 16 + c16) ^ ((row & 7) << 3))] = (f16)zt[r];
    }
    __syncthreads();
    f16x8 ztA[2];
#pragma unroll
    for (int kb = 0; kb < 2; ++kb)
      ztA[kb] = ld8(ztL + c16 * 64 + ((kb * 32 + q4 * 8) ^ swz));

#pragma unroll
    for (int j = 0; j < 2; ++j) {
      f32x4 ad = {}, at = {};
      ad = mfma32(ztA[0], dr1B[j][0], ad);
      ad = mfma32(ztA[1], dr1B[j][1], ad);
      at = mfma32(ztA[0], tau1B[j][0], at);
      at = mfma32(ztA[1], tau1B[j][1], at);
      float bt = fmaf(tm, t1t[j], tau1b[j]);
      int colbase = (w * 2 + j) * 16 + c16;
#pragma unroll
      for (int r = 0; r < 4; ++r) {
        int row = q4 * 4 + r;
        int off = row * 128 + (colbase ^ ((row & 7) << 3));
        hdL[off] = (f16)ftanh(ad[r] + dr1b[j]);
        htL[off] = (f16)ftanh(at[r] + bt);
      }
    }
    __syncthreads();
    f16x8 hdA[4], htA[4];
#pragma unroll
    for (int kb = 0; kb < 4; ++kb) {
      int ko = c16 * 128 + ((kb * 32 + q4 * 8) ^ swz);
      hdA[kb] = ld8(hdL + ko);
      htA[kb] = ld8(htL + ko);
    }

    {
      int row16 = (w * 16 + c16) * 128;
      f32x4 dv = {}, tr = {}, za = {};
#pragma unroll
      for (int kb = 0; kb < 4; ++kb) {
        f16x8 bd = ld8(dr2s + row16 + ((kb * 32 + q4 * 8) ^ swz));
        f16x8 bt2 = ld8(tau2s + row16 + ((kb * 32 + q4 * 8) ^ swz));
        dv = mfma32(hdA[kb], bd, dv);
        tr = mfma32(htA[kb], bt2, tr);
      }
      za = mfma32(ztA[0], AB[0], za);
      za = mfma32(ztA[1], AB[1], za);
#pragma unroll
      for (int r = 0; r < 4; ++r) {
        float traw = tr[r] + tau2b;
        float sp = (traw > 15.f) ? traw : log1pf(__expf(traw));
        float sg = 1.f / (1.f + __expf(-(sp + 1e-6f)));
        float inv = 1.f / fmaf(4.95f, sg, 0.05f);
        float ztv = zt[r];
        float dz = za[r] + inv * ((dv[r] + dr2b) - ztv);
        zt[r] = fmaf(0.03125f, dz, ztv);
      }
    }
    tm += 0.03125f;
  }

  // final FC: wave does 3 of 12 col-tiles; only rows 0..7 (q4 < 2) stored
#pragma unroll
  for (int r = 0; r < 4; ++r) {
    int row = q4 * 4 + r;
    ztL[row * 64 + ((w * 16 + c16) ^ ((row & 7) << 3))] = (f16)zt[r];
  }
  __syncthreads();
  f16x8 zA2[2];
#pragma unroll
  for (int kb = 0; kb < 2; ++kb)
    zA2[kb] = ld8(ztL + c16 * 64 + ((kb * 32 + q4 * 8) ^ swz));
#pragma unroll
  for (int j = 0; j < 3; ++j) {
    int ct = w * 3 + j;
    f32x4 acc = {};
    acc = mfma32(zA2[0], ld8(fch + (ct * 16 + c16) * 64 + q4 * 8), acc);
    acc = mfma32(zA2[1], ld8(fch + (ct * 16 + c16) * 64 + 32 + q4 * 8), acc);
    float bias = fb[512 + ct * 16 + c16];
    if (q4 < 2) {
#pragma unroll
      for (int r = 0; r < 4; ++r)
        out[(size_t)(b0 + q4 * 4 + r) * 192 + ct * 16 + c16] = acc[r] + bias;
    }
  }
}

extern "C" void kernel_launch(void* const* d_in, const int* in_sizes, int n_in,
                              void* d_out, int out_size, void* d_ws, size_t ws_size,
                              hipStream_t stream) {
  const float* x = (const float*)d_in[0];
  const float* conv_w = (const float*)d_in[1];
  const float* conv_b = (const float*)d_in[2];
  const float* cls = (const float*)d_in[3];
  const float* attn_w = (const float*)d_in[4];
  const float* attn_b = (const float*)d_in[5];
  const float* out_w = (const float*)d_in[6];
  const float* out_b = (const float*)d_in[7];
  const float* ln1_g = (const float*)d_in[8];
  const float* ln1_b = (const float*)d_in[9];
  const float* ln2_g = (const float*)d_in[10];
  const float* ln2_b = (const float*)d_in[11];
  const float* ff1_w = (const float*)d_in[12];
  const float* ff1_b = (const float*)d_in[13];
  const float* ff2_w = (const float*)d_in[14];
  const float* ff2_b = (const float*)d_in[15];
  const float* B_mat = (const float*)d_in[16];
  const float* dr1_w = (const float*)d_in[17];
  const float* dr1_b = (const float*)d_in[18];
  const float* dr2_w = (const float*)d_in[19];
  const float* dr2_b = (const float*)d_in[20];
  const float* tau1_w = (const float*)d_in[21];
  const float* tau1_b = (const float*)d_in[22];
  const float* tau2_w = (const float*)d_in[23];
  const float* tau2_b = (const float*)d_in[24];
  const float* fc_w = (const float*)d_in[25];
  const float* fc_b = (const float*)d_in[26];

  char* wsb = (char*)d_ws;
  float* zcb = (float*)(wsb + 101376);     // 4096*64 f32
  f16* tfw = (f16*)(wsb + 1149952);        // 188416 B
  float* pecb = (float*)(wsb + 1338368);   // 8192 B

  prep_kernel<<<130, 64, 0, stream>>>(B_mat, dr1_w, dr1_b, dr2_w, dr2_b,
                                      tau1_w, tau1_b, tau2_w, tau2_b,
                                      fc_w, fc_b, wsb);
  prep_tf<<<376, 256, 0, stream>>>(conv_w, attn_w, out_w, ff1_w, ff2_w, conv_b,
                                   tfw, pecb);
  tf_kernel<<<4096, 256, 0, stream>>>(x, tfw, pecb, cls, attn_b, out_b,
                                      ln1_g, ln1_b, ln2_g, ln2_b, ff1_b, ff2_b, zcb);
  ode_kernel<<<512, 256, 0, stream>>>(wsb, zcb, (float*)d_out);
}

// Round 13
// 242.670 us; speedup vs baseline: 1.4462x; 1.4462x over previous
//
#include <hip/hip_runtime.h>
#include <hip/hip_fp16.h>
#include <math.h>

#define DEV static __device__ __forceinline__

typedef _Float16 f16;
typedef __attribute__((ext_vector_type(4))) _Float16 f16x4;
typedef __attribute__((ext_vector_type(8))) _Float16 f16x8;
typedef __attribute__((ext_vector_type(4))) float f32x4;

DEV f16x8 ld8(const f16* p) { return *(const f16x8*)p; }
DEV f32x4 mfma32(f16x8 a, f16x8 b, f32x4 c) {
  return __builtin_amdgcn_mfma_f32_16x16x32_f16(a, b, c, 0, 0, 0);
}
DEV float ftanh(float x) {
  float e = __expf(2.f * x);
  return 1.f - 2.f / (e + 1.f);
}

// ---------------- prep: pack ODE+FC weights f16 row-major [out][in] ----------------
__global__ __launch_bounds__(64) void prep_kernel(
    const float* __restrict__ Bm,
    const float* __restrict__ dr1_w, const float* __restrict__ dr1_b,
    const float* __restrict__ dr2_w, const float* __restrict__ dr2_b,
    const float* __restrict__ tau1_w, const float* __restrict__ tau1_b,
    const float* __restrict__ tau2_w, const float* __restrict__ tau2_b,
    const float* __restrict__ fc_w, const float* __restrict__ fc_b,
    char* __restrict__ wsb) {
  f16* dr1h = (f16*)(wsb);
  f16* tau1h = (f16*)(wsb + 16384);
  f16* dr2h = (f16*)(wsb + 32768);
  f16* tau2h = (f16*)(wsb + 49152);
  f16* Ah = (f16*)(wsb + 65536);
  f16* fch = (f16*)(wsb + 73728);
  float* fb = (float*)(wsb + 98304);

  const int t = threadIdx.x, blk = blockIdx.x;
  if (blk < 16) {
    int row = blk * 4 + (t >> 4), c0 = 4 * (t & 15);
    float a0 = 0.f, a1 = 0.f, a2 = 0.f, a3 = 0.f;
    for (int m = 0; m < 64; ++m) {
      float br = Bm[m * 64 + row];
      a0 = fmaf(br, Bm[m * 64 + c0 + 0], a0);
      a1 = fmaf(br, Bm[m * 64 + c0 + 1], a1);
      a2 = fmaf(br, Bm[m * 64 + c0 + 2], a2);
      a3 = fmaf(br, Bm[m * 64 + c0 + 3], a3);
    }
    Ah[row * 64 + c0 + 0] = (f16)(-a0);
    Ah[row * 64 + c0 + 1] = (f16)(-a1);
    Ah[row * 64 + c0 + 2] = (f16)(-a2);
    Ah[row * 64 + c0 + 3] = (f16)(-a3);
  } else if (blk < 48) {
    int idx = (blk - 16) * 64 + t;
    int row = idx >> 4, c0 = 4 * (idx & 15);
#pragma unroll
    for (int j = 0; j < 4; ++j) {
      dr1h[row * 64 + c0 + j] = (f16)dr1_w[row * 64 + c0 + j];
      tau1h[row * 64 + c0 + j] = (f16)tau1_w[row * 65 + c0 + j];
    }
  } else if (blk < 80) {
    int idx = (blk - 48) * 64 + t;
    int row = idx >> 5, c0 = 4 * (idx & 31);
#pragma unroll
    for (int j = 0; j < 4; ++j) {
      dr2h[row * 128 + c0 + j] = (f16)dr2_w[row * 128 + c0 + j];
      tau2h[row * 128 + c0 + j] = (f16)tau2_w[row * 128 + c0 + j];
    }
  } else if (blk < 128) {
    int idx = (blk - 80) * 64 + t;
    int row = idx >> 4, c0 = 4 * (idx & 15);
#pragma unroll
    for (int j = 0; j < 4; ++j)
      fch[row * 64 + c0 + j] = (f16)fc_w[row * 64 + c0 + j];
  } else {
    for (int i = (blk - 128) * 64 + t; i < 704; i += 128) {
      float v;
      if (i < 128) v = dr1_b[i];
      else if (i < 256) v = tau1_b[i - 128];
      else if (i < 320) v = dr2_b[i - 256];
      else if (i < 384) v = tau2_b[i - 320];
      else if (i < 512) v = tau1_w[(i - 384) * 65 + 64];
      else v = fc_b[i - 512];
      fb[i] = v;
    }
  }
}

// ---------------- prep_tf: tf weights -> f16 (unpadded row-major) + PE table -------
__global__ __launch_bounds__(256) void prep_tf(
    const float* __restrict__ conv_w, const float* __restrict__ attn_w,
    const float* __restrict__ out_w, const float* __restrict__ ff1_w,
    const float* __restrict__ ff2_w, const float* __restrict__ conv_b,
    f16* __restrict__ tfw, float* __restrict__ pecb) {
  int idx = blockIdx.x * 256 + threadIdx.x;
  if (idx >= 96256) return;
  if (idx >= 94208) {
    int e = idx - 94208;  // 0..2047
    int i = 1 + (e >> 6), dd = e & 63;
    float freq = __expf(-0.14391157f * (float)(dd & ~1));
    float ang = (float)i * freq;
    pecb[e] = ((dd & 1) ? cosf(ang) : sinf(ang)) + conv_b[dd];
    return;
  }
  float v;
  if (idx < 8192) {
    int dd = idx >> 7, k = idx & 127;
    v = conv_w[dd * 128 + (k & 7) * 16 + (k >> 3)];
  } else {
    int r = idx - 8192;
    int l = r / 28672, q = r - l * 28672;
    if (q < 12288) v = attn_w[l * 12288 + q];
    else if (q < 16384) v = out_w[l * 4096 + (q - 12288)];
    else if (q < 22528) v = ff1_w[l * 6144 + (q - 16384)];
    else v = ff2_w[l * 6144 + (q - 22528)];
  }
  tfw[idx] = (f16)v;
}

// ---------------- transformer v6.1: f16 master, 38.8 KB LDS, relaxed VGPR bound ----
__global__ __launch_bounds__(256, 3) void tf_kernel(
    const float* __restrict__ x, const f16* __restrict__ tfw,
    const float* __restrict__ pecb, const float* __restrict__ cls,
    const float* __restrict__ attn_b, const float* __restrict__ out_b,
    const float* __restrict__ ln1_g, const float* __restrict__ ln1_b,
    const float* __restrict__ ln2_g, const float* __restrict__ ln2_b,
    const float* __restrict__ ff1_b, const float* __restrict__ ff2_b,
    float* __restrict__ zc) {
  __shared__ __align__(16) unsigned char SH[38800];
  f16* Zh = (f16*)SH;
  f16* Qh = (f16*)(SH + 6912);
  f16* Kh = (f16*)(SH + 13824);
  f16* VT = (f16*)(SH + 20736);
  f16* P = (f16*)(SH + 25856);
  f16* Sx = (f16*)(SH + 6912);
  f16* f1h = (f16*)(SH + 13824);
  f16* oh = Qh;

  const int t = threadIdx.x;
  const int b = blockIdx.x;
  const int w = t >> 6, lane = t & 63;
  const int c16 = lane & 15, q4 = lane >> 4;
  const int dcol = w * 16 + c16;
  const int d4 = w * 16 + q4 * 4;
  const int nrow = t >> 2, nl4 = t & 3;

  // ---- prologue ----
  {
    const float4* xg = (const float4*)(x + (size_t)b * 4096);
    for (int i = t; i < 1024; i += 256) {
      int n = i >> 5, jj = i & 31;
      float4 v = xg[i];
      *(f16x4*)(Sx + n * 136 + jj * 4) = f16x4{(f16)v.x, (f16)v.y, (f16)v.z, (f16)v.w};
    }
    unsigned* zp = (unsigned*)(Zh + 33 * 72);
    for (int i = t; i < 540; i += 256) zp[i] = 0u;
    uint4 z4{0, 0, 0, 0};
    uint4* pp = (uint4*)P;
    for (int i = t; i < 809; i += 256) pp[i] = z4;
    if (t < 64) Zh[t] = (f16)(cls[t] + ((t & 1) ? 1.0f : 0.0f));
  }
  __syncthreads();

  // ---- patch embed (swapped) + PE table ----
  {
    f16x8 cw[4];
#pragma unroll
    for (int kb = 0; kb < 4; ++kb)
      cw[kb] = ld8(tfw + dcol * 128 + kb * 32 + q4 * 8);
#pragma unroll
    for (int it = 0; it < 2; ++it) {
      f32x4 acc = {};
#pragma unroll
      for (int kb = 0; kb < 4; ++kb)
        acc = mfma32(cw[kb], ld8(Sx + (it * 16 + c16) * 136 + kb * 32 + q4 * 8), acc);
      int n = it * 16 + c16;
      float4 pe = *(const float4*)(pecb + n * 64 + d4);
      *(f16x4*)(Zh + (n + 1) * 72 + d4) =
          f16x4{(f16)(acc[0] + pe.x), (f16)(acc[1] + pe.y),
                (f16)(acc[2] + pe.z), (f16)(acc[3] + pe.w)};
    }
  }
  __syncthreads();

  for (int l = 0; l < 3; ++l) {
    const f16* lw = tfw + 8192 + l * 28672;
    const int ntile = (l == 2) ? 1 : 3;
    const bool has2 = (w < 2);
    const int j1f = has2 ? (w + 4) * 16 + c16 : dcol;
    const int j1b = has2 ? (w + 4) * 16 + q4 * 4 : d4;

    // ---- layer-resident weight A-fragments ----
    f16x8 wq0 = ld8(lw + dcol * 64 + q4 * 8);
    f16x8 wq1 = ld8(lw + dcol * 64 + 32 + q4 * 8);
    f16x8 wk0 = ld8(lw + (64 + dcol) * 64 + q4 * 8);
    f16x8 wk1 = ld8(lw + (64 + dcol) * 64 + 32 + q4 * 8);
    f16x8 wv0 = ld8(lw + (128 + dcol) * 64 + q4 * 8);
    f16x8 wv1 = ld8(lw + (128 + dcol) * 64 + 32 + q4 * 8);
    f16x8 ow0 = ld8(lw + 12288 + dcol * 64 + q4 * 8);
    f16x8 ow1 = ld8(lw + 12288 + dcol * 64 + 32 + q4 * 8);
    f16x8 f1w00 = ld8(lw + 16384 + dcol * 64 + q4 * 8);
    f16x8 f1w01 = ld8(lw + 16384 + dcol * 64 + 32 + q4 * 8);
    f16x8 f1w10 = ld8(lw + 16384 + j1f * 64 + q4 * 8);
    f16x8 f1w11 = ld8(lw + 16384 + j1f * 64 + 32 + q4 * 8);
    f16x8 fw20 = ld8(lw + 22528 + dcol * 96 + q4 * 8);
    f16x8 fw21 = ld8(lw + 22528 + dcol * 96 + 32 + q4 * 8);
    f16x8 fw22 = ld8(lw + 22528 + dcol * 96 + 64 + q4 * 8);
    float4 bq4 = *(const float4*)(attn_b + l * 192 + d4);
    float4 bk4 = *(const float4*)(attn_b + l * 192 + 64 + d4);
    float bv = attn_b[l * 192 + 128 + dcol];
    float4 ob4 = *(const float4*)(out_b + l * 64 + d4);
    float4 f1b0 = *(const float4*)(ff1_b + l * 96 + d4);
    float4 f1b1 = *(const float4*)(ff1_b + l * 96 + j1b);
    float4 f2b4 = *(const float4*)(ff2_b + l * 64 + d4);

    // ---- P1: qkv ----
    {
      f16x8 zr0[3], zr1[3];
#pragma unroll
      for (int it = 0; it < 3; ++it) {
        zr0[it] = ld8(Zh + (it * 16 + c16) * 72 + q4 * 8);
        zr1[it] = ld8(Zh + (it * 16 + c16) * 72 + 32 + q4 * 8);
      }
#pragma unroll
      for (int it = 0; it < 3; ++it) {
        f32x4 aq = {}, ak = {}, av = {};
        aq = mfma32(wq0, zr0[it], aq); aq = mfma32(wq1, zr1[it], aq);
        ak = mfma32(wk0, zr0[it], ak); ak = mfma32(wk1, zr1[it], ak);
        av = mfma32(zr0[it], wv0, av); av = mfma32(zr1[it], wv1, av);
        int i = it * 16 + c16;
        *(f16x4*)(Qh + i * 72 + d4) =
            f16x4{(f16)((aq[0] + bq4.x) * 0.25f), (f16)((aq[1] + bq4.y) * 0.25f),
                  (f16)((aq[2] + bq4.z) * 0.25f), (f16)((aq[3] + bq4.w) * 0.25f)};
        *(f16x4*)(Kh + i * 72 + d4) =
            f16x4{(f16)(ak[0] + bk4.x), (f16)(ak[1] + bk4.y),
                  (f16)(ak[2] + bk4.z), (f16)(ak[3] + bk4.w)};
        if (it < 2) {
          *(f16x4*)(VT + dcol * 40 + it * 16 + q4 * 4) =
              f16x4{(f16)(av[0] + bv), (f16)(av[1] + bv),
                    (f16)(av[2] + bv), (f16)(av[3] + bv)};
        } else if (q4 == 0) {
          VT[dcol * 40 + 32] = (f16)(av[0] + bv);
        }
      }
    }

    // ---- P2: S^T = K.Q^T -> masked softmax -> O^T = V^T.P^T ----
    {
      f16x8 zf = {};
      f16x8 kf0 = (q4 < 2) ? ld8(Kh + (c16) * 72 + w * 16 + q4 * 8) : zf;
      f16x8 kf1 = (q4 < 2) ? ld8(Kh + (16 + c16) * 72 + w * 16 + q4 * 8) : zf;
      f16x8 kf2 = (q4 < 2) ? ld8(Kh + (32 + c16) * 72 + w * 16 + q4 * 8) : zf;
      f16x8 vf = ld8(VT + dcol * 40 + q4 * 8);
      float vt32[4];
#pragma unroll
      for (int r = 0; r < 4; ++r) vt32[r] = (float)VT[(d4 + r) * 40 + 32];
      f16* Ph = P + w * 1320;
#pragma unroll
      for (int it = 0; it < 3; ++it) {
        if (it >= ntile) break;
        f16x8 qf = (q4 < 2) ? ld8(Qh + (it * 16 + c16) * 72 + w * 16 + q4 * 8) : zf;
        f32x4 zz = {};
        f32x4 s0 = mfma32(kf0, qf, zz);
        f32x4 s1 = mfma32(kf1, qf, zz);
        f32x4 s2 = mfma32(kf2, qf, zz);
        float m = -1e30f;
#pragma unroll
        for (int r = 0; r < 4; ++r) m = fmaxf(m, fmaxf(s0[r], s1[r]));
        if (q4 == 0) m = fmaxf(m, s2[0]);
        m = fmaxf(m, __shfl_xor(m, 16));
        m = fmaxf(m, __shfl_xor(m, 32));
        float e0[4], e1[4], su = 0.f;
#pragma unroll
        for (int r = 0; r < 4; ++r) {
          e0[r] = __expf(s0[r] - m); e1[r] = __expf(s1[r] - m);
          su += e0[r] + e1[r];
        }
        float e2 = (q4 == 0) ? __expf(s2[0] - m) : 0.f;
        su += e2;
        su += __shfl_xor(su, 16);
        su += __shfl_xor(su, 32);
        float inv = 1.f / su;
        int i = it * 16 + c16;
        if (i < 33) {
          *(f16x4*)(Ph + i * 40 + q4 * 4) =
              f16x4{(f16)(e0[0] * inv), (f16)(e0[1] * inv),
                    (f16)(e0[2] * inv), (f16)(e0[3] * inv)};
          *(f16x4*)(Ph + i * 40 + 16 + q4 * 4) =
              f16x4{(f16)(e1[0] * inv), (f16)(e1[1] * inv),
                    (f16)(e1[2] * inv), (f16)(e1[3] * inv)};
          if (q4 == 0) Ph[i * 40 + 32] = (f16)(e2 * inv);
        }
      }
#pragma unroll
      for (int it = 0; it < 3; ++it) {
        if (it >= ntile) break;
        int i = it * 16 + c16;
        f16x8 pf = ld8(Ph + i * 40 + q4 * 8);
        f32x4 zz = {};
        f32x4 acc = mfma32(vf, pf, zz);
        float p32 = (float)Ph[i * 40 + 32];
        *(f16x4*)(oh + i * 72 + d4) =
            f16x4{(f16)(acc[0] + vt32[0] * p32), (f16)(acc[1] + vt32[1] * p32),
                  (f16)(acc[2] + vt32[2] * p32), (f16)(acc[3] + vt32[3] * p32)};
      }
    }
    __syncthreads();

    // ---- P3: out-proj + residual RMW on f16 master ----
#pragma unroll
    for (int it = 0; it < 3; ++it) {
      if (it >= ntile) break;
      int i = it * 16 + c16;
      f32x4 acc = {};
      acc = mfma32(ow0, ld8(oh + i * 72 + q4 * 8), acc);
      acc = mfma32(ow1, ld8(oh + i * 72 + 32 + q4 * 8), acc);
      if (it < 2 || c16 == 0) {
        f16x4 zr = *(f16x4*)(Zh + i * 72 + d4);
        *(f16x4*)(Zh + i * 72 + d4) =
            f16x4{(f16)((float)zr[0] + acc[0] + ob4.x),
                  (f16)((float)zr[1] + acc[1] + ob4.y),
                  (f16)((float)zr[2] + acc[2] + ob4.z),
                  (f16)((float)zr[3] + acc[3] + ob4.w)};
      }
    }
    __syncthreads();

    // ---- P4: fused LN1 ----
    {
      int rows = (l == 2) ? 16 : 33;
      if (nrow < rows) {
        f16* zr = Zh + nrow * 72 + nl4 * 16;
        f16x8 h0 = ld8(zr), h1 = ld8(zr + 8);
        float v[16];
#pragma unroll
        for (int j = 0; j < 8; ++j) { v[j] = (float)h0[j]; v[8 + j] = (float)h1[j]; }
        float su = 0.f, ss = 0.f;
#pragma unroll
        for (int j = 0; j < 16; ++j) { su += v[j]; ss = fmaf(v[j], v[j], ss); }
        su += __shfl_xor(su, 1); ss += __shfl_xor(ss, 1);
        su += __shfl_xor(su, 2); ss += __shfl_xor(ss, 2);
        float m = su * 0.015625f;
        float rr = rsqrtf(ss * 0.015625f - m * m + 1e-5f);
        const float4* gg = (const float4*)(ln1_g + l * 64 + nl4 * 16);
        const float4* bb = (const float4*)(ln1_b + l * 64 + nl4 * 16);
#pragma unroll
        for (int g4 = 0; g4 < 4; ++g4) {
          float4 G = gg[g4], B = bb[g4];
          *(f16x4*)(zr + g4 * 4) =
              f16x4{(f16)((v[g4 * 4 + 0] - m) * rr * G.x + B.x),
                    (f16)((v[g4 * 4 + 1] - m) * rr * G.y + B.y),
                    (f16)((v[g4 * 4 + 2] - m) * rr * G.z + B.z),
                    (f16)((v[g4 * 4 + 3] - m) * rr * G.w + B.w)};
        }
      }
    }
    __syncthreads();

    // ---- P5: ff1 ----
    {
      f16x8 zr0[3], zr1[3];
#pragma unroll
      for (int it = 0; it < 3; ++it) {
        zr0[it] = ld8(Zh + (it * 16 + c16) * 72 + q4 * 8);
        zr1[it] = ld8(Zh + (it * 16 + c16) * 72 + 32 + q4 * 8);
      }
#pragma unroll
      for (int it = 0; it < 3; ++it) {
        if (it >= ntile) break;
        int i = it * 16 + c16;
        f32x4 acc = {};
        acc = mfma32(f1w00, zr0[it], acc);
        acc = mfma32(f1w01, zr1[it], acc);
        *(f16x4*)(f1h + i * 104 + d4) =
            f16x4{(f16)fmaxf(acc[0] + f1b0.x, 0.f), (f16)fmaxf(acc[1] + f1b0.y, 0.f),
                  (f16)fmaxf(acc[2] + f1b0.z, 0.f), (f16)fmaxf(acc[3] + f1b0.w, 0.f)};
        if (has2) {
          f32x4 a2 = {};
          a2 = mfma32(f1w10, zr0[it], a2);
          a2 = mfma32(f1w11, zr1[it], a2);
          *(f16x4*)(f1h + i * 104 + j1b) =
              f16x4{(f16)fmaxf(a2[0] + f1b1.x, 0.f), (f16)fmaxf(a2[1] + f1b1.y, 0.f),
                    (f16)fmaxf(a2[2] + f1b1.z, 0.f), (f16)fmaxf(a2[3] + f1b1.w, 0.f)};
        }
      }
    }
    __syncthreads();

    // ---- P6: ff2 + residual RMW ----
#pragma unroll
    for (int it = 0; it < 3; ++it) {
      if (it >= ntile) break;
      int i = it * 16 + c16;
      f32x4 acc = {};
      acc = mfma32(fw20, ld8(f1h + i * 104 + q4 * 8), acc);
      acc = mfma32(fw21, ld8(f1h + i * 104 + 32 + q4 * 8), acc);
      acc = mfma32(fw22, ld8(f1h + i * 104 + 64 + q4 * 8), acc);
      if (it < 2 || c16 == 0) {
        f16x4 zr = *(f16x4*)(Zh + i * 72 + d4);
        *(f16x4*)(Zh + i * 72 + d4) =
            f16x4{(f16)((float)zr[0] + acc[0] + f2b4.x),
                  (f16)((float)zr[1] + acc[1] + f2b4.y),
                  (f16)((float)zr[2] + acc[2] + f2b4.z),
                  (f16)((float)zr[3] + acc[3] + f2b4.w)};
      }
    }
    __syncthreads();

    // ---- P7: fused LN2 (+ zc on last layer) ----
    {
      int rows = (l == 2) ? 1 : 33;
      if (nrow < rows) {
        f16* zr = Zh + nrow * 72 + nl4 * 16;
        f16x8 h0 = ld8(zr), h1 = ld8(zr + 8);
        float v[16];
#pragma unroll
        for (int j = 0; j < 8; ++j) { v[j] = (float)h0[j]; v[8 + j] = (float)h1[j]; }
        float su = 0.f, ss = 0.f;
#pragma unroll
        for (int j = 0; j < 16; ++j) { su += v[j]; ss = fmaf(v[j], v[j], ss); }
        su += __shfl_xor(su, 1); ss += __shfl_xor(ss, 1);
        su += __shfl_xor(su, 2); ss += __shfl_xor(ss, 2);
        float m = su * 0.015625f;
        float rr = rsqrtf(ss * 0.015625f - m * m + 1e-5f);
        const float4* gg = (const float4*)(ln2_g + l * 64 + nl4 * 16);
        const float4* bb = (const float4*)(ln2_b + l * 64 + nl4 * 16);
        if (l == 2) {
          float4* zo = (float4*)(zc + (size_t)b * 64 + nl4 * 16);
#pragma unroll
          for (int g4 = 0; g4 < 4; ++g4) {
            float4 G = gg[g4], B = bb[g4];
            zo[g4] = make_float4((v[g4 * 4 + 0] - m) * rr * G.x + B.x,
                                 (v[g4 * 4 + 1] - m) * rr * G.y + B.y,
                                 (v[g4 * 4 + 2] - m) * rr * G.z + B.z,
                                 (v[g4 * 4 + 3] - m) * rr * G.w + B.w);
          }
        } else {
#pragma unroll
          for (int g4 = 0; g4 < 4; ++g4) {
            float4 G = gg[g4], B = bb[g4];
            *(f16x4*)(zr + g4 * 4) =
                f16x4{(f16)((v[g4 * 4 + 0] - m) * rr * G.x + B.x),
                      (f16)((v[g4 * 4 + 1] - m) * rr * G.y + B.y),
                      (f16)((v[g4 * 4 + 2] - m) * rr * G.z + B.z),
                      (f16)((v[g4 * 4 + 3] - m) * rr * G.w + B.w)};
          }
        }
      }
    }
    __syncthreads();
  }
}

// ---------------- ODE v3 (round-11, known-good ~60 us): 4 waves, 16 rows/block -----
__global__ __launch_bounds__(256, 1) void ode_kernel(
    const char* __restrict__ wsb, const float* __restrict__ zc,
    float* __restrict__ out) {
  const f16* dr1h = (const f16*)(wsb);
  const f16* tau1h = (const f16*)(wsb + 16384);
  const f16* Ah = (const f16*)(wsb + 65536);
  const f16* fch = (const f16*)(wsb + 73728);
  const float* fb = (const float*)(wsb + 98304);

  __shared__ __align__(16) f16 dr2s[64 * 128];
  __shared__ __align__(16) f16 tau2s[64 * 128];
  __shared__ __align__(16) f16 ztL[16 * 64];
  __shared__ __align__(16) f16 hdL[16 * 128];
  __shared__ __align__(16) f16 htL[16 * 128];

  const int t = threadIdx.x;
  const int w = t >> 6;
  const int lane = t & 63;
  const int c16 = lane & 15, q4 = lane >> 4;
  const int b0 = blockIdx.x * 16;
  const int swz = (c16 & 7) << 3;

  for (int i = t; i < 2048; i += 256) {
    int m = i >> 10, gi = i & 1023, row = gi >> 4, g = gi & 15;
    uint4 v = ((const uint4*)(wsb + 32768 + m * 16384))[gi];
    ((uint4*)(m ? tau2s : dr2s))[row * 16 + (g ^ (row & 7))] = v;
  }

  f16x8 dr1B[2][2], tau1B[2][2], AB[2];
#pragma unroll
  for (int j = 0; j < 2; ++j) {
    int cth = w * 2 + j;
#pragma unroll
    for (int kb = 0; kb < 2; ++kb) {
      dr1B[j][kb] = ld8(dr1h + (cth * 16 + c16) * 64 + kb * 32 + q4 * 8);
      tau1B[j][kb] = ld8(tau1h + (cth * 16 + c16) * 64 + kb * 32 + q4 * 8);
    }
  }
#pragma unroll
  for (int kb = 0; kb < 2; ++kb)
    AB[kb] = ld8(Ah + (w * 16 + c16) * 64 + kb * 32 + q4 * 8);
  float dr1b[2], tau1b[2], t1t[2];
#pragma unroll
  for (int j = 0; j < 2; ++j) {
    int cc = (w * 2 + j) * 16 + c16;
    dr1b[j] = fb[cc]; tau1b[j] = fb[128 + cc]; t1t[j] = fb[384 + cc];
  }
  float dr2b = fb[256 + w * 16 + c16];
  float tau2b = fb[320 + w * 16 + c16];

  float zt[4];
#pragma unroll
  for (int r = 0; r < 4; ++r)
    zt[r] = zc[(size_t)(b0 + q4 * 4 + r) * 64 + w * 16 + c16];

  __syncthreads();

  float tm = 0.f;
  for (int s = 0; s < 32; ++s) {
#pragma unroll
    for (int r = 0; r < 4; ++r) {
      int row = q4 * 4 + r;
      ztL[row * 64 + ((w * 16 + c16) ^ ((row & 7) << 3))] = (f16)zt[r];
    }
    __syncthreads();
    f16x8 ztA[2];
#pragma unroll
    for (int kb = 0; kb < 2; ++kb)
      ztA[kb] = ld8(ztL + c16 * 64 + ((kb * 32 + q4 * 8) ^ swz));

#pragma unroll
    for (int j = 0; j < 2; ++j) {
      f32x4 ad = {}, at = {};
      ad = mfma32(ztA[0], dr1B[j][0], ad);
      ad = mfma32(ztA[1], dr1B[j][1], ad);
      at = mfma32(ztA[0], tau1B[j][0], at);
      at = mfma32(ztA[1], tau1B[j][1], at);
      float bt = fmaf(tm, t1t[j], tau1b[j]);
      int colbase = (w * 2 + j) * 16 + c16;
#pragma unroll
      for (int r = 0; r < 4; ++r) {
        int row = q4 * 4 + r;
        int off = row * 128 + (colbase ^ ((row & 7) << 3));
        hdL[off] = (f16)ftanh(ad[r] + dr1b[j]);
        htL[off] = (f16)ftanh(at[r] + bt);
      }
    }
    __syncthreads();
    f16x8 hdA[4], htA[4];
#pragma unroll
    for (int kb = 0; kb < 4; ++kb) {
      int ko = c16 * 128 + ((kb * 32 + q4 * 8) ^ swz);
      hdA[kb] = ld8(hdL + ko);
      htA[kb] = ld8(htL + ko);
    }

    {
      int row16 = (w * 16 + c16) * 128;
      f32x4 dv = {}, tr = {}, za = {};
#pragma unroll
      for (int kb = 0; kb < 4; ++kb) {
        f16x8 bd = ld8(dr2s + row16 + ((kb * 32 + q4 * 8) ^ swz));
        f16x8 bt2 = ld8(tau2s + row16 + ((kb * 32 + q4 * 8) ^ swz));
        dv = mfma32(hdA[kb], bd, dv);
        tr = mfma32(htA[kb], bt2, tr);
      }
      za = mfma32(ztA[0], AB[0], za);
      za = mfma32(ztA[1], AB[1], za);
#pragma unroll
      for (int r = 0; r < 4; ++r) {
        float traw = tr[r] + tau2b;
        float sp = (traw > 15.f) ? traw : log1pf(__expf(traw));
        float sg = 1.f / (1.f + __expf(-(sp + 1e-6f)));
        float inv = 1.f / fmaf(4.95f, sg, 0.05f);
        float ztv = zt[r];
        float dz = za[r] + inv * ((dv[r] + dr2b) - ztv);
        zt[r] = fmaf(0.03125f, dz, ztv);
      }
    }
    tm += 0.03125f;
  }

#pragma unroll
  for (int r = 0; r < 4; ++r) {
    int row = q4 * 4 + r;
    ztL[row * 64 + ((w * 16 + c16) ^ ((row & 7) << 3))] = (f16)zt[r];
  }
  __syncthreads();
  f16x8 zA2[2];
#pragma unroll
  for (int kb = 0; kb < 2; ++kb)
    zA2[kb] = ld8(ztL + c16 * 64 + ((kb * 32 + q4 * 8) ^ swz));
#pragma unroll
  for (int j = 0; j < 3; ++j) {
    int ct = w * 3 + j;
    f32x4 acc = {};
    acc = mfma32(zA2[0], ld8(fch + (ct * 16 + c16) * 64 + q4 * 8), acc);
    acc = mfma32(zA2[1], ld8(fch + (ct * 16 + c16) * 64 + 32 + q4 * 8), acc);
    float bias = fb[512 + ct * 16 + c16];
#pragma unroll
    for (int r = 0; r < 4; ++r)
      out[(size_t)(b0 + q4 * 4 + r) * 192 + ct * 16 + c16] = acc[r] + bias;
  }
}

extern "C" void kernel_launch(void* const* d_in, const int* in_sizes, int n_in,
                              void* d_out, int out_size, void* d_ws, size_t ws_size,
                              hipStream_t stream) {
  const float* x = (const float*)d_in[0];
  const float* conv_w = (const float*)d_in[1];
  const float* conv_b = (const float*)d_in[2];
  const float* cls = (const float*)d_in[3];
  const float* attn_w = (const float*)d_in[4];
  const float* attn_b = (const float*)d_in[5];
  const float* out_w = (const float*)d_in[6];
  const float* out_b = (const float*)d_in[7];
  const float* ln1_g = (const float*)d_in[8];
  const float* ln1_b = (const float*)d_in[9];
  const float* ln2_g = (const float*)d_in[10];
  const float* ln2_b = (const float*)d_in[11];
  const float* ff1_w = (const float*)d_in[12];
  const float* ff1_b = (const float*)d_in[13];
  const float* ff2_w = (const float*)d_in[14];
  const float* ff2_b = (const float*)d_in[15];
  const float* B_mat = (const float*)d_in[16];
  const float* dr1_w = (const float*)d_in[17];
  const float* dr1_b = (const float*)d_in[18];
  const float* dr2_w = (const float*)d_in[19];
  const float* dr2_b = (const float*)d_in[20];
  const float* tau1_w = (const float*)d_in[21];
  const float* tau1_b = (const float*)d_in[22];
  const float* tau2_w = (const float*)d_in[23];
  const float* tau2_b = (const float*)d_in[24];
  const float* fc_w = (const float*)d_in[25];
  const float* fc_b = (const float*)d_in[26];

  char* wsb = (char*)d_ws;
  float* zcb = (float*)(wsb + 101376);     // 4096*64 f32
  f16* tfw = (f16*)(wsb + 1149952);        // 188416 B
  float* pecb = (float*)(wsb + 1338368);   // 8192 B

  prep_kernel<<<130, 64, 0, stream>>>(B_mat, dr1_w, dr1_b, dr2_w, dr2_b,
                                      tau1_w, tau1_b, tau2_w, tau2_b,
                                      fc_w, fc_b, wsb);
  prep_tf<<<376, 256, 0, stream>>>(conv_w, attn_w, out_w, ff1_w, ff2_w, conv_b,
                                   tfw, pecb);
  tf_kernel<<<4096, 256, 0, stream>>>(x, tfw, pecb, cls, attn_b, out_b,
                                      ln1_g, ln1_b, ln2_g, ln2_b, ff1_b, ff2_b, zcb);
  ode_kernel<<<256, 256, 0, stream>>>(wsb, zcb, (float*)d_out);
}